// Round 4
// baseline (85.644 us; speedup 1.0000x reference)
//
#include <hip/hip_runtime.h>

#define GRID 256
#define NTHR 256

// ws layout (ints/floats, all re-poisoned 0xAA before each timed launch —
// flag protocol only requires "initial value != 1", so no memset needed):
//   flags1[256] | flags2[256] | cpart[256] | part_w[256] | part_mn[256] | part_mx[256]

#define AGENT __HIP_MEMORY_SCOPE_AGENT

__global__ __launch_bounds__(256) void SPL_fused(const float* __restrict__ pred,
                                                 const float* __restrict__ tgt,
                                                 int* __restrict__ ws_i,
                                                 float* __restrict__ out) {
    int* flags1 = ws_i;
    int* flags2 = ws_i + 256;
    int* cpart  = ws_i + 512;
    float* part_w  = (float*)(ws_i + 768);
    float* part_mn = part_w + 256;
    float* part_mx = part_w + 512;

    __shared__ float sP[1280], sT[1280];   // 10 rows x 128 cols, zero-padded
    __shared__ float vsP[256], vsT[256];   // vertical 9-sums
    __shared__ float red[12];
    __shared__ int   ired[4];

    int b = blockIdx.x;
    int t = threadIdx.x;
    int m  = b >> 6;              // image 0..3
    int r2 = (b & 63) << 1;       // first of this block's 2 output rows
    const float* p = pred + (m << 14);
    const float* q = tgt  + (m << 14);

    // ---- phase 1: separable edge-corrected 9x9 box mean; dists stay in regs ----
#pragma unroll
    for (int s = 0; s < 5; ++s) {
        int k   = t + s * 256;    // 0..1279
        int rr  = k >> 7;
        int cc  = k & 127;
        int grw = r2 - 4 + rr;
        bool ok = (unsigned)grw < 128u;
        sP[k] = ok ? p[(grw << 7) + cc] : 0.f;
        sT[k] = ok ? q[(grw << 7) + cc] : 0.f;
    }
    __syncthreads();

    int orow = t >> 7;            // 0/1
    int col  = t & 127;
    int row  = r2 + orow;

    float vp = 0.f, vt = 0.f;
    int vb = orow * 128 + col;
#pragma unroll
    for (int di = 0; di < 9; ++di) {
        vp += sP[vb + di * 128];
        vt += sT[vb + di * 128];
    }
    vsP[t] = vp; vsT[t] = vt;
    __syncthreads();

    float sp = 0.f, st = 0.f;
    int rbase = t & ~127;
#pragma unroll
    for (int dj = -4; dj <= 4; ++dj) {
        int jj = col + dj;
        if ((unsigned)jj < 128u) { sp += vsP[rbase + jj]; st += vsT[rbase + jj]; }
    }

    int   rc  = min(row, 4) + min(127 - row, 4) + 1;
    int   cn  = min(col, 4) + min(127 - col, 4) + 1;
    float den = (float)(rc * cn);
    float pv  = sP[(orow + 4) * 128 + col];
    float tv  = sT[(orow + 4) * 128 + col];
    float pd  = pv - sp / den;    // live across the grid barrier
    float td  = tv - st / den;

    float w = 1.f;
    if (tv >= 0.5f) w = 2.f;
    if (tv >= 2.f)  w = 5.f;
    if (tv >= 5.f)  w = 10.f;
    if (tv >= 10.f) w = 30.f;
    float d  = pv - tv;
    float s1 = w * d * d;
    float mn = fminf(pd, td);
    float mx = fmaxf(pd, td);

    for (int o = 32; o > 0; o >>= 1) {
        s1 += __shfl_down(s1, o, 64);
        mn  = fminf(mn, __shfl_down(mn, o, 64));
        mx  = fmaxf(mx, __shfl_down(mx, o, 64));
    }
    int lane = t & 63, wid = t >> 6;
    if (lane == 0) { red[wid] = s1; red[4 + wid] = mn; red[8 + wid] = mx; }
    __syncthreads();
    if (t == 0) {
        __hip_atomic_store(&part_w[b],  red[0] + red[1] + red[2] + red[3],
                           __ATOMIC_RELAXED, AGENT);
        __hip_atomic_store(&part_mn[b], fminf(fminf(red[4], red[5]), fminf(red[6], red[7])),
                           __ATOMIC_RELAXED, AGENT);
        __hip_atomic_store(&part_mx[b], fmaxf(fmaxf(red[8], red[9]), fmaxf(red[10], red[11])),
                           __ATOMIC_RELAXED, AGENT);
        __hip_atomic_store(&flags1[b], 1, __ATOMIC_RELEASE, AGENT);  // publish
    }

    // ---- grid barrier 1: no init needed (poison/zero != 1) ----
    // thread t waits for block t's flag (256 threads x 256 flags)
    while (__hip_atomic_load(&flags1[t], __ATOMIC_ACQUIRE, AGENT) != 1) { }
    __syncthreads();

    // ---- phase 2: every block derives identical lo/hi, counts its own pixels ----
    float mn2 = __hip_atomic_load(&part_mn[t], __ATOMIC_RELAXED, AGENT);
    float mx2 = __hip_atomic_load(&part_mx[t], __ATOMIC_RELAXED, AGENT);
    for (int o = 32; o > 0; o >>= 1) {
        mn2 = fminf(mn2, __shfl_down(mn2, o, 64));
        mx2 = fmaxf(mx2, __shfl_down(mx2, o, 64));
    }
    if (lane == 0) { red[wid] = mn2; red[4 + wid] = mx2; }
    __syncthreads();
    float lo = fminf(fminf(red[0], red[1]), fminf(red[2], red[3]));
    float hi = fmaxf(fmaxf(red[4], red[5]), fmaxf(red[6], red[7]));
    float dx = (hi - lo) / 999.0f;

    // #{k in [0,1000) : lo + k*dx in [min(pd,td), max(pd,td))}  (exact int)
    float a  = fminf(pd, td);
    float b2 = fmaxf(pd, td);
    int ka = (int)ceilf((a - lo) / dx);
    int kb = (int)ceilf((b2 - lo) / dx);
    ka = max(ka, 0);
    kb = min(kb, 1000);
    int cnt = max(kb - ka, 0);
    for (int o = 32; o > 0; o >>= 1) cnt += __shfl_down(cnt, o, 64);
    if (lane == 0) ired[wid] = cnt;
    __syncthreads();
    if (t == 0) {
        __hip_atomic_store(&cpart[b], ired[0] + ired[1] + ired[2] + ired[3],
                           __ATOMIC_RELAXED, AGENT);
        __hip_atomic_store(&flags2[b], 1, __ATOMIC_RELEASE, AGENT);
    }

    // ---- block 0: final combine (fixed-order, deterministic) ----
    if (b == 0) {
        while (__hip_atomic_load(&flags2[t], __ATOMIC_ACQUIRE, AGENT) != 1) { }
        int   c  = __hip_atomic_load(&cpart[t],  __ATOMIC_RELAXED, AGENT);
        float ws = __hip_atomic_load(&part_w[t], __ATOMIC_RELAXED, AGENT);
        for (int o = 32; o > 0; o >>= 1) {
            c  += __shfl_down(c, o, 64);
            ws += __shfl_down(ws, o, 64);
        }
        if (lane == 0) { ired[wid] = c; red[wid] = ws; }
        __syncthreads();
        if (t == 0) {
            long long tot = (long long)ired[0] + ired[1] + ired[2] + ired[3];
            float wtot = red[0] + red[1] + red[2] + red[3];
            float  wmse = wtot * (1.0f / 65536.0f);
            double crps = (double)tot * (double)dx / 65536.0;
            out[0] = 1e-4f * wmse + (float)crps;
        }
    }
}

extern "C" void kernel_launch(void* const* d_in, const int* in_sizes, int n_in,
                              void* d_out, int out_size, void* d_ws, size_t ws_size,
                              hipStream_t stream) {
    const float* pred = (const float*)d_in[0];
    const float* tgt  = (const float*)d_in[1];
    SPL_fused<<<GRID, NTHR, 0, stream>>>(pred, tgt, (int*)d_ws, (float*)d_out);
}

// Round 5
// 66.946 us; speedup vs baseline: 1.2793x; 1.2793x over previous
//
#include <hip/hip_runtime.h>

// ws layout: part[768] floats | float2 dist[65536] (512 KB)

__global__ __launch_bounds__(256) void SPL_kA(const float* __restrict__ pred,
                                              const float* __restrict__ tgt,
                                              float* __restrict__ part,
                                              float2* __restrict__ dist) {
    __shared__ float sP[1280], sT[1280];   // 10 rows x 128 cols, zero-padded
    __shared__ float vsP[256], vsT[256];   // vertical 9-sums
    __shared__ float red[12];

    int b = blockIdx.x;
    int t = threadIdx.x;
    int m  = b >> 6;              // image 0..3
    int r2 = (b & 63) << 1;       // first of the 2 output rows
    const float* p = pred + (m << 14);
    const float* q = tgt  + (m << 14);

    // stage rows r2-4 .. r2+5 (zero-pad out-of-image)
#pragma unroll
    for (int s = 0; s < 5; ++s) {
        int k   = t + s * 256;    // 0..1279
        int rr  = k >> 7;
        int cc  = k & 127;
        int grw = r2 - 4 + rr;
        bool ok = (unsigned)grw < 128u;
        sP[k] = ok ? p[(grw << 7) + cc] : 0.f;
        sT[k] = ok ? q[(grw << 7) + cc] : 0.f;
    }
    __syncthreads();

    int orow = t >> 7;            // 0/1
    int col  = t & 127;
    int row  = r2 + orow;

    // vertical 9-sum
    float vp = 0.f, vt = 0.f;
    int vb = orow * 128 + col;
#pragma unroll
    for (int di = 0; di < 9; ++di) {
        vp += sP[vb + di * 128];
        vt += sT[vb + di * 128];
    }
    vsP[t] = vp; vsT[t] = vt;
    __syncthreads();

    // horizontal 9-sum with column bounds
    float sp = 0.f, st = 0.f;
    int rbase = t & ~127;
#pragma unroll
    for (int dj = -4; dj <= 4; ++dj) {
        int jj = col + dj;
        if ((unsigned)jj < 128u) { sp += vsP[rbase + jj]; st += vsT[rbase + jj]; }
    }

    int   rc  = min(row, 4) + min(127 - row, 4) + 1;
    int   cn  = min(col, 4) + min(127 - col, 4) + 1;
    float den = (float)(rc * cn);
    float pv  = sP[(orow + 4) * 128 + col];
    float tv  = sT[(orow + 4) * 128 + col];
    float pd  = pv - sp / den;
    float td  = tv - st / den;

    dist[(b << 8) + t] = make_float2(pd, td);

    // threshold-weighted MSE term
    float w = 1.f;
    if (tv >= 0.5f) w = 2.f;
    if (tv >= 2.f)  w = 5.f;
    if (tv >= 5.f)  w = 10.f;
    if (tv >= 10.f) w = 30.f;
    float d  = pv - tv;
    float s  = w * d * d;
    float mn = fminf(pd, td);
    float mx = fmaxf(pd, td);

    for (int o = 32; o > 0; o >>= 1) {
        s  += __shfl_down(s, o, 64);
        mn  = fminf(mn, __shfl_down(mn, o, 64));
        mx  = fmaxf(mx, __shfl_down(mx, o, 64));
    }
    int lane = t & 63, wid = t >> 6;
    if (lane == 0) { red[wid] = s; red[4 + wid] = mn; red[8 + wid] = mx; }
    __syncthreads();
    if (t == 0) {
        part[b]       = red[0] + red[1] + red[2] + red[3];
        part[256 + b] = fminf(fminf(red[4], red[5]), fminf(red[6], red[7]));
        part[512 + b] = fmaxf(fmaxf(red[8], red[9]), fmaxf(red[10], red[11]));
    }
}

// 1 block x 1024 threads: reduce partials -> lo/hi/wmse, analytic CRPS count, final loss
__global__ __launch_bounds__(1024) void SPL_kB(const float* __restrict__ part,
                                               const float4* __restrict__ dist4,
                                               float* __restrict__ out) {
    __shared__ float rs[16], rmn[16], rmx[16];
    __shared__ int   rci[16];
    __shared__ float bc[3];   // lo, hi, wmse-sum

    int t = threadIdx.x;
    int lane = t & 63, wid = t >> 6;   // 16 waves

    float s = 0.f, mn = 3.4e38f, mx = -3.4e38f;
    if (t < 256) { s = part[t]; mn = part[256 + t]; mx = part[512 + t]; }
    for (int o = 32; o > 0; o >>= 1) {
        s  += __shfl_down(s, o, 64);
        mn  = fminf(mn, __shfl_down(mn, o, 64));
        mx  = fmaxf(mx, __shfl_down(mx, o, 64));
    }
    if (lane == 0) { rs[wid] = s; rmn[wid] = mn; rmx[wid] = mx; }
    __syncthreads();
    if (t == 0) {
        float ss = 0.f, m1 = 3.4e38f, m2 = -3.4e38f;
        for (int i = 0; i < 16; ++i) {
            ss += rs[i]; m1 = fminf(m1, rmn[i]); m2 = fmaxf(m2, rmx[i]);
        }
        bc[0] = m1; bc[1] = m2; bc[2] = ss;
    }
    __syncthreads();

    float lo = bc[0], hi = bc[1];
    float dx = (hi - lo) / 999.0f;
    float inv_dx = 1.0f / dx;

    // count grid points x_k = lo + k*dx, k in [0,1000), in [min,max) per pixel;
    // two pixels per float4 load, 32 iters x 1024 threads = 65536 pixels
    int cnt = 0;
#pragma unroll 4
    for (int it = 0; it < 32; ++it) {
        float4 d = dist4[it * 1024 + t];
        float a0 = fminf(d.x, d.y), b0 = fmaxf(d.x, d.y);
        float a1 = fminf(d.z, d.w), b1 = fmaxf(d.z, d.w);
        int ka0 = (int)ceilf((a0 - lo) * inv_dx);
        int kb0 = (int)ceilf((b0 - lo) * inv_dx);
        int ka1 = (int)ceilf((a1 - lo) * inv_dx);
        int kb1 = (int)ceilf((b1 - lo) * inv_dx);
        ka0 = max(ka0, 0); kb0 = min(kb0, 1000);
        ka1 = max(ka1, 0); kb1 = min(kb1, 1000);
        cnt += max(kb0 - ka0, 0) + max(kb1 - ka1, 0);
    }
    for (int o = 32; o > 0; o >>= 1) cnt += __shfl_down(cnt, o, 64);
    if (lane == 0) rci[wid] = cnt;
    __syncthreads();
    if (t == 0) {
        long long tot = 0;
        for (int i = 0; i < 16; ++i) tot += rci[i];
        float  wmse = bc[2] * (1.0f / 65536.0f);
        double crps = (double)tot * (double)dx / 65536.0;
        out[0] = 1e-4f * wmse + (float)crps;
    }
}

extern "C" void kernel_launch(void* const* d_in, const int* in_sizes, int n_in,
                              void* d_out, int out_size, void* d_ws, size_t ws_size,
                              hipStream_t stream) {
    const float* pred = (const float*)d_in[0];
    const float* tgt  = (const float*)d_in[1];
    float*  part = (float*)d_ws;                 // 768 floats
    float2* dist = (float2*)(part + 768);        // 65536 float2 = 512 KB
    float*  out  = (float*)d_out;

    SPL_kA<<<256, 256, 0, stream>>>(pred, tgt, part, dist);
    SPL_kB<<<1, 1024, 0, stream>>>(part, (const float4*)dist, out);
}